// Round 2
// baseline (106.767 us; speedup 1.0000x reference)
//
#include <hip/hip_runtime.h>

#define PAGE_SHIFT 4
#define PAGE_MASK 15

// Kernel 1: single-block dual exclusive prefix sum over B (<= 4096) elements.
// starts[i]   = sum_{j<i} (seq[j] - pre[j])
// new_start[i]= sum_{j<i} (ceil(seq[j]/16) - ceil(pre[j]/16))
__global__ __launch_bounds__(1024) void scan_kernel(const int* __restrict__ pre_lens,
                                                    const int* __restrict__ seq_lens,
                                                    int B,
                                                    int* __restrict__ starts,
                                                    int* __restrict__ new_start) {
    __shared__ int s_ext[1024];
    __shared__ int s_np[1024];
    const int t = threadIdx.x;

    int e[4], np[4];
    int sum_e = 0, sum_np = 0;
#pragma unroll
    for (int j = 0; j < 4; ++j) {
        int i = t * 4 + j;
        int pe = (i < B) ? pre_lens[i] : 0;
        int se = (i < B) ? seq_lens[i] : 0;
        int ex = se - pe;
        int pb = (pe + PAGE_MASK) >> PAGE_SHIFT;
        int pa = (se + PAGE_MASK) >> PAGE_SHIFT;
        e[j] = ex;
        np[j] = pa - pb;
        sum_e += ex;
        sum_np += np[j];
    }
    s_ext[t] = sum_e;
    s_np[t] = sum_np;
    __syncthreads();

    // Hillis-Steele inclusive scan over 1024 thread sums.
    for (int off = 1; off < 1024; off <<= 1) {
        int ve = 0, vn = 0;
        if (t >= off) { ve = s_ext[t - off]; vn = s_np[t - off]; }
        __syncthreads();
        s_ext[t] += ve;
        s_np[t] += vn;
        __syncthreads();
    }

    int base_e = (t > 0) ? s_ext[t - 1] : 0;
    int base_n = (t > 0) ? s_np[t - 1] : 0;
#pragma unroll
    for (int j = 0; j < 4; ++j) {
        int i = t * 4 + j;
        if (i < B) {
            starts[i] = base_e;
            new_start[i] = base_n;
        }
        base_e += e[j];
        base_n += np[j];
    }
}

// Kernel 2: one block per sequence; coalesced writes of its extend-token slots.
__global__ __launch_bounds__(256) void assign_kernel(const int* __restrict__ pre_lens,
                                                     const int* __restrict__ seq_lens,
                                                     const int* __restrict__ last_loc,
                                                     const int* __restrict__ free_page,
                                                     const int* __restrict__ starts,
                                                     const int* __restrict__ new_start,
                                                     int* __restrict__ out,
                                                     int n_free) {
    const int b = blockIdx.x;
    const int pre = pre_lens[b];
    const int seqv = seq_lens[b];
    const int ext = seqv - pre;
    const int start = starts[b];
    const int ll1 = last_loc[b] + 1;
    const int pb = (pre + PAGE_MASK) >> PAGE_SHIFT;
    const int boundary = pb << PAGE_SHIFT;
    const int ns = new_start[b];

    for (int o = threadIdx.x; o < ext; o += blockDim.x) {
        int p = pre + o;
        int v;
        if (p < boundary) {
            v = ll1 + o;  // fill the partially-used existing page
        } else {
            int k = (p >> PAGE_SHIFT) - pb;      // which new page
            int idx = ns + k;
            idx = min(max(idx, 0), n_free - 1);  // match reference clip
            v = free_page[idx] * (1 << PAGE_SHIFT) + (p & PAGE_MASK);
        }
        out[start + o] = v;
    }
}

extern "C" void kernel_launch(void* const* d_in, const int* in_sizes, int n_in,
                              void* d_out, int out_size, void* d_ws, size_t ws_size,
                              hipStream_t stream) {
    const int* pre_lens  = (const int*)d_in[0];
    const int* seq_lens  = (const int*)d_in[1];
    const int* last_loc  = (const int*)d_in[2];
    const int* free_page = (const int*)d_in[3];
    const int B = in_sizes[0];
    const int n_free = in_sizes[3];

    int* starts    = (int*)d_ws;            // B ints
    int* new_start = ((int*)d_ws) + B;      // B ints

    scan_kernel<<<1, 1024, 0, stream>>>(pre_lens, seq_lens, B, starts, new_start);
    assign_kernel<<<B, 256, 0, stream>>>(pre_lens, seq_lens, last_loc, free_page,
                                         starts, new_start, (int*)d_out, n_free);
}

// Round 3
// 102.259 us; speedup vs baseline: 1.0441x; 1.0441x over previous
//
#include <hip/hip_runtime.h>

#define PAGE_SHIFT 4
#define PAGE_MASK 15
#define TOK_PER_BLOCK 1024   // tokens per assign block (256 thr x 4 tokens)
#define MAX_EXT_TILES 8      // ext < 8192 by construction; guarded by loop anyway

// ---------------- Kernel 1: dual exclusive prefix sum over B elements ----------------
// starts[i]    = sum_{j<i} (seq[j] - pre[j])
// new_start[i] = sum_{j<i} (ceil(seq[j]/16) - ceil(pre[j]/16))
__global__ __launch_bounds__(1024) void scan_kernel(const int* __restrict__ pre_lens,
                                                    const int* __restrict__ seq_lens,
                                                    int B,
                                                    int* __restrict__ starts,
                                                    int* __restrict__ new_start) {
    __shared__ int w_e[16];
    __shared__ int w_n[16];
    const int t = threadIdx.x;
    const int lane = t & 63;
    const int wv = t >> 6;
    const int i0 = t * 4;

    int pe[4], se[4];
    if (i0 + 3 < B) {
        int4 pv = *reinterpret_cast<const int4*>(pre_lens + i0);
        int4 sv = *reinterpret_cast<const int4*>(seq_lens + i0);
        pe[0] = pv.x; pe[1] = pv.y; pe[2] = pv.z; pe[3] = pv.w;
        se[0] = sv.x; se[1] = sv.y; se[2] = sv.z; se[3] = sv.w;
    } else {
#pragma unroll
        for (int j = 0; j < 4; ++j) {
            pe[j] = (i0 + j < B) ? pre_lens[i0 + j] : 0;
            se[j] = (i0 + j < B) ? seq_lens[i0 + j] : 0;
        }
    }

    int e[4], np[4];
    int tot_e = 0, tot_n = 0;
#pragma unroll
    for (int j = 0; j < 4; ++j) {
        e[j] = se[j] - pe[j];
        int pb = (pe[j] + PAGE_MASK) >> PAGE_SHIFT;
        int pa = (se[j] + PAGE_MASK) >> PAGE_SHIFT;
        np[j] = pa - pb;
        tot_e += e[j];
        tot_n += np[j];
    }

    // wave-64 inclusive scan of per-thread totals
    int sc_e = tot_e, sc_n = tot_n;
#pragma unroll
    for (int d = 1; d < 64; d <<= 1) {
        int ve = __shfl_up(sc_e, d, 64);
        int vn = __shfl_up(sc_n, d, 64);
        if (lane >= d) { sc_e += ve; sc_n += vn; }
    }
    if (lane == 63) { w_e[wv] = sc_e; w_n[wv] = sc_n; }
    __syncthreads();

    // wave 0 scans the 16 wave totals (inclusive)
    if (wv == 0) {
        int ve = (lane < 16) ? w_e[lane] : 0;
        int vn = (lane < 16) ? w_n[lane] : 0;
#pragma unroll
        for (int d = 1; d < 16; d <<= 1) {
            int ae = __shfl_up(ve, d, 64);
            int an = __shfl_up(vn, d, 64);
            if (lane >= d) { ve += ae; vn += an; }
        }
        if (lane < 16) { w_e[lane] = ve; w_n[lane] = vn; }
    }
    __syncthreads();

    int base_e = (wv > 0 ? w_e[wv - 1] : 0) + (sc_e - tot_e);  // exclusive base for this thread
    int base_n = (wv > 0 ? w_n[wv - 1] : 0) + (sc_n - tot_n);

    if (i0 + 3 < B) {
        int4 oe, on;
        oe.x = base_e;            on.x = base_n;
        oe.y = oe.x + e[0];       on.y = on.x + np[0];
        oe.z = oe.y + e[1];       on.z = on.y + np[1];
        oe.w = oe.z + e[2];       on.w = on.z + np[2];
        *reinterpret_cast<int4*>(starts + i0) = oe;
        *reinterpret_cast<int4*>(new_start + i0) = on;
    } else {
#pragma unroll
        for (int j = 0; j < 4; ++j) {
            if (i0 + j < B) { starts[i0 + j] = base_e; new_start[i0 + j] = base_n; }
            base_e += e[j];
            base_n += np[j];
        }
    }
}

// ---------------- Kernel 2: slot assignment, tiled 2D grid ----------------
__device__ __forceinline__ int slot_value(int o, int pre, int boundary, int pb, int ll1,
                                          int ns, const int* __restrict__ fp, int n_free) {
    int p = pre + o;
    if (p < boundary) return ll1 + o;                 // fill existing partial page
    int idx = ns + (p >> PAGE_SHIFT) - pb;            // which new page
    idx = min(max(idx, 0), n_free - 1);               // match reference clip
    return fp[idx] * (1 << PAGE_SHIFT) + (p & PAGE_MASK);
}

__global__ __launch_bounds__(256) void assign_kernel(const int* __restrict__ pre_lens,
                                                     const int* __restrict__ seq_lens,
                                                     const int* __restrict__ last_loc,
                                                     const int* __restrict__ free_page,
                                                     const int* __restrict__ starts,
                                                     const int* __restrict__ new_start,
                                                     int* __restrict__ out,
                                                     int n_free) {
    const int b = blockIdx.x;
    const int pre = pre_lens[b];
    const int ext = seq_lens[b] - pre;
    const int start = starts[b];
    const int al = (-start) & 3;               // head tokens so that start+al is 16B-aligned
    const int ty = blockIdx.y;

    for (int obase = al + ty * TOK_PER_BLOCK; ; obase += gridDim.y * TOK_PER_BLOCK) {
        bool any = (obase < ext) || (ty == 0 && obase == al);  // ty0 also handles the head peel
        if (!any) return;

        const int ll1 = last_loc[b] + 1;
        const int pb = (pre + PAGE_MASK) >> PAGE_SHIFT;
        const int boundary = pb << PAGE_SHIFT;
        const int ns = new_start[b];

        // head peel (scalar, <4 tokens) — only once, by tile 0's first pass
        if (ty == 0 && obase == al) {
            int o = (int)threadIdx.x;
            if (o < al && o < ext) {
                out[start + o] = slot_value(o, pre, boundary, pb, ll1, ns, free_page, n_free);
            }
        }

        int o = obase + (int)threadIdx.x * 4;
        if (o + 3 < ext) {
            int4 v;
            v.x = slot_value(o,     pre, boundary, pb, ll1, ns, free_page, n_free);
            v.y = slot_value(o + 1, pre, boundary, pb, ll1, ns, free_page, n_free);
            v.z = slot_value(o + 2, pre, boundary, pb, ll1, ns, free_page, n_free);
            v.w = slot_value(o + 3, pre, boundary, pb, ll1, ns, free_page, n_free);
            *reinterpret_cast<int4*>(out + start + o) = v;   // (start+o) % 4 == 0
        } else {
            for (int oo = o; oo < ext; ++oo) {
                out[start + oo] = slot_value(oo, pre, boundary, pb, ll1, ns, free_page, n_free);
            }
        }
        // ext < 8192 and gridDim.y*TOK_PER_BLOCK = 8192, so this loop runs once;
        // the for-structure is just a safety net for larger ext.
        if (obase + gridDim.y * TOK_PER_BLOCK >= ext) return;
    }
}

extern "C" void kernel_launch(void* const* d_in, const int* in_sizes, int n_in,
                              void* d_out, int out_size, void* d_ws, size_t ws_size,
                              hipStream_t stream) {
    const int* pre_lens  = (const int*)d_in[0];
    const int* seq_lens  = (const int*)d_in[1];
    const int* last_loc  = (const int*)d_in[2];
    const int* free_page = (const int*)d_in[3];
    const int B = in_sizes[0];
    const int n_free = in_sizes[3];

    int* starts    = (int*)d_ws;            // B ints
    int* new_start = ((int*)d_ws) + B;      // B ints

    scan_kernel<<<1, 1024, 0, stream>>>(pre_lens, seq_lens, B, starts, new_start);
    dim3 grid(B, MAX_EXT_TILES);
    assign_kernel<<<grid, 256, 0, stream>>>(pre_lens, seq_lens, last_loc, free_page,
                                            starts, new_start, (int*)d_out, n_free);
}